// Round 2
// baseline (964.654 us; speedup 1.0000x reference)
//
#include <hip/hip_runtime.h>

#define NV 256                 // V
#define NC 64                  // C_OUT
#define VW 65536               // V*V
#define NE1 1048576            // N*C*V = 64*64*256 = 2^20 (out1/x/xoc/post elems)

// ---------------------------------------------------------------------------
// k1: xo_c[n][c][v] = bo[c] + sum_i wo[c][i] * xo[n][i][v]
// idx decode: v = idx&255, c = (idx>>8)&63, n = idx>>14  (20 bits total).
// ---------------------------------------------------------------------------
__global__ __launch_bounds__(256) void k1_xoc(
    const float* __restrict__ xo, const float* __restrict__ wo,
    const float* __restrict__ bo, float* __restrict__ xoc)
{
    const int idx = blockIdx.x * 256 + threadIdx.x;   // < 2^20
    const int v = idx & 255;
    const int c = (idx >> 8) & 63;
    const int n = idx >> 14;                          // < 64
    const float* xon = xo + (size_t)n * 64 * NV;
    const float* wrow = wo + c * 64;                  // block-uniform -> s_load
    float s = bo[c];
#pragma unroll
    for (int i = 0; i < 64; ++i)
        s = fmaf(wrow[i], xon[i * NV + v], s);
    xoc[idx] = s;
}

// ---------------------------------------------------------------------------
// k2: per-position MLP 5->16->32->64 (relu, relu, sigmoid) producing A_out,
// fused with gating accumulation post[n,c,w] += xo_c[n,c,v] * A_out[n,c,v,w].
// Thread = one w column; block covers a 16-v chunk; grid = (16 chunks, 64 n).
// Weights are wave-uniform with literal indices -> SGPR operands for the FMAs.
// ---------------------------------------------------------------------------
__global__ __launch_bounds__(256) void k2_mlp_gate(
    const float* __restrict__ A,
    const float* __restrict__ w1, const float* __restrict__ b1,
    const float* __restrict__ w2, const float* __restrict__ b2,
    const float* __restrict__ w3, const float* __restrict__ b3,
    const float* __restrict__ xoc,
    float* __restrict__ Aout, float* __restrict__ post)
{
    const int w = threadIdx.x;
    const int vbase = blockIdx.x * 16;
    const int n = blockIdx.y;

    const float* An  = A    + (size_t)n * 6  * VW;
    float*       Aon = Aout + (size_t)n * NC * VW;
    const float* xn  = xoc  + (size_t)n * NC * NV;

    float acc[NC];
#pragma unroll
    for (int c = 0; c < NC; ++c) acc[c] = 0.0f;

    for (int vi = 0; vi < 16; ++vi) {
        const int v = vbase + vi;
        const int off = v * NV + w;
        const float a0 = An[0 * VW + off];
        const float a1 = An[1 * VW + off];
        const float a2 = An[2 * VW + off];
        const float a3 = An[3 * VW + off];
        const float a4 = An[4 * VW + off];

        float h1[16];
#pragma unroll
        for (int j = 0; j < 16; ++j) {
            float s = b1[j];
            s = fmaf(w1[j * 5 + 0], a0, s);
            s = fmaf(w1[j * 5 + 1], a1, s);
            s = fmaf(w1[j * 5 + 2], a2, s);
            s = fmaf(w1[j * 5 + 3], a3, s);
            s = fmaf(w1[j * 5 + 4], a4, s);
            h1[j] = fmaxf(s, 0.0f);
        }

        float h2[32];
#pragma unroll
        for (int j = 0; j < 32; ++j) {
            float s = b2[j];
#pragma unroll
            for (int i = 0; i < 16; ++i)
                s = fmaf(w2[j * 16 + i], h1[i], s);
            h2[j] = fmaxf(s, 0.0f);
        }

#pragma unroll
        for (int c = 0; c < NC; ++c) {
            float s = b3[c];
#pragma unroll
            for (int i = 0; i < 32; ++i)
                s = fmaf(w3[c * 32 + i], h2[i], s);
            const float val = 1.0f / (1.0f + __expf(-s));
            Aon[(size_t)c * VW + off] = val;              // coalesced across w
            acc[c] = fmaf(xn[c * NV + v], val, acc[c]);   // block-uniform load
        }
    }

    float* pn = post + (size_t)n * NC * NV;
#pragma unroll
    for (int c = 0; c < NC; ++c)
        atomicAdd(&pn[c * NV + w], acc[c]);               // coalesced across w
}

// ---------------------------------------------------------------------------
// k3: out1 = x * sigmoid(post)
// ---------------------------------------------------------------------------
__global__ __launch_bounds__(256) void k3_gate(
    const float* __restrict__ x, const float* __restrict__ post,
    float* __restrict__ out1)
{
    const int idx = blockIdx.x * 256 + threadIdx.x;       // < 2^20
    const float p = 1.0f / (1.0f + __expf(-post[idx]));
    out1[idx] = x[idx] * p;
}

extern "C" void kernel_launch(void* const* d_in, const int* in_sizes, int n_in,
                              void* d_out, int out_size, void* d_ws, size_t ws_size,
                              hipStream_t stream)
{
    const float* x  = (const float*)d_in[0];
    const float* xo = (const float*)d_in[1];
    const float* A  = (const float*)d_in[2];
    const float* w1 = (const float*)d_in[3];
    const float* b1 = (const float*)d_in[4];
    const float* w2 = (const float*)d_in[5];
    const float* b2 = (const float*)d_in[6];
    const float* w3 = (const float*)d_in[7];
    const float* b3 = (const float*)d_in[8];
    const float* wo = (const float*)d_in[9];
    const float* bo = (const float*)d_in[10];

    // Output tuple layout: out1 (N*C*V = 2^20) then A_out (N*C*V*V).
    float* out1 = (float*)d_out;
    float* Aout = (float*)d_out + NE1;

    // Workspace: xo_c (4 MB) + posterior-logit accumulator (4 MB).
    float* xoc  = (float*)d_ws;
    float* post = (float*)d_ws + NE1;

    hipMemsetAsync(post, 0, (size_t)NE1 * sizeof(float), stream);
    k1_xoc<<<NE1 / 256, 256, 0, stream>>>(xo, wo, bo, xoc);
    k2_mlp_gate<<<dim3(16, 64), 256, 0, stream>>>(A, w1, b1, w2, b2, w3, b3,
                                                  xoc, Aout, post);
    k3_gate<<<NE1 / 256, 256, 0, stream>>>(x, post, out1);
}

// Round 3
// 410.362 us; speedup vs baseline: 2.3507x; 2.3507x over previous
//
#include <hip/hip_runtime.h>
#include <hip/hip_bf16.h>

#define NV 256                 // V
#define NC 64                  // C_OUT
#define VW 65536               // V*V
#define NE1 1048576            // N*C*V = 2^20

typedef __attribute__((ext_vector_type(8))) short bf16x8;   // 8 bf16 = 4 VGPRs
typedef __attribute__((ext_vector_type(16))) float f32x16;  // MFMA 32x32 acc

static __device__ __forceinline__ short f2bf(float x) {
    union { __hip_bfloat16 b; short s; } u;
    u.b = __float2bfloat16(x);          // RNE
    return u.s;
}

// ---------------------------------------------------------------------------
// k1: xo_c[n][c][v] = bo[c] + sum_i wo[c][i] * xo[n][i][v]
// ---------------------------------------------------------------------------
__global__ __launch_bounds__(256) void k1_xoc(
    const float* __restrict__ xo, const float* __restrict__ wo,
    const float* __restrict__ bo, float* __restrict__ xoc)
{
    const int idx = blockIdx.x * 256 + threadIdx.x;   // < 2^20
    const int v = idx & 255;
    const int c = (idx >> 8) & 63;
    const int n = idx >> 14;
    const float* xon = xo + (size_t)n * 64 * NV;
    const float* wrow = wo + c * 64;                  // block-uniform -> s_load
    float s = bo[c];
#pragma unroll
    for (int i = 0; i < 64; ++i)
        s = fmaf(wrow[i], xon[i * NV + v], s);
    xoc[idx] = s;
}

// ---------------------------------------------------------------------------
// k2: per-position MLP. Phase 1 (per-thread VALU): layers 1-2 (5->16->32),
// h2 packed bf16 into swizzled LDS. Phase 2 (per-wave MFMA): layer 3 as
// D[32c x 32w] = W3[32c x 16k] @ H2[16k x 32w] pairs (K=32 via 2 chained
// mfma_f32_32x32x16_bf16), fused sigmoid + A_out store + gate accumulate.
// Block = (16-v chunk, n); 4 waves; wave q owns w in [64q, 64q+64).
// ---------------------------------------------------------------------------
__global__ __launch_bounds__(256) void k2_mfma(
    const float* __restrict__ A,
    const float* __restrict__ w1, const float* __restrict__ b1,
    const float* __restrict__ w2, const float* __restrict__ b2,
    const float* __restrict__ w3, const float* __restrict__ b3,
    const float* __restrict__ xoc,
    float* __restrict__ Aout, float* __restrict__ post)
{
    // [pos=256][chunk=4] 16B chunks of h2 (8 bf16 each), chunk XOR-swizzled
    // by ((pos>>1)&3) on BOTH write and read (rule: both-sides-or-neither).
    __shared__ bf16x8 h2s[1024];                 // 16 KB
    __shared__ float  xocs[NC][16];              // 4 KB  [c][vi]

    const int t    = threadIdx.x;
    const int q    = t >> 6;                     // wave id 0..3
    const int lane = t & 63;
    const int lo   = lane & 31;
    const int hi   = lane >> 5;
    const int vbase = blockIdx.x * 16;
    const int n    = blockIdx.y;

    // ---- stage xoc[n, :, vbase:vbase+16] into LDS (once per block)
    {
        const int c = t >> 2, j0 = (t & 3) << 2;
        const float* src = xoc + (size_t)n * (NC * NV) + c * NV + vbase + j0;
#pragma unroll
        for (int j = 0; j < 4; ++j) xocs[c][j0 + j] = src[j];
    }

    // ---- preload W3 A-fragments (bf16) once: A[row=c][k], row=lo(+32ct),
    //      k = 16h + 8*hi + e  (32x32x16 A layout: row=l&31, k=(l>>5)*8+e)
    bf16x8 af[2][2];
#pragma unroll
    for (int ct = 0; ct < 2; ++ct)
#pragma unroll
        for (int h = 0; h < 2; ++h) {
            const int c  = (ct << 5) + lo;
            const int kb = (h << 4) + (hi << 3);
            const float* wp = w3 + c * 32 + kb;
            bf16x8 pk;
#pragma unroll
            for (int e = 0; e < 8; ++e) pk[e] = f2bf(wp[e]);
            af[ct][h] = pk;
        }

    // ---- bias as accumulator-init: dinit[ct][r] = b3[c(ct,r,hi)]
    f32x16 dinit[2];
#pragma unroll
    for (int ct = 0; ct < 2; ++ct)
#pragma unroll
        for (int r = 0; r < 16; ++r)
            dinit[ct][r] = b3[(ct << 5) + (r & 3) + ((r >> 2) << 3) + (hi << 2)];

    float gacc[2][2][16];
#pragma unroll
    for (int ct = 0; ct < 2; ++ct)
#pragma unroll
        for (int T = 0; T < 2; ++T)
#pragma unroll
            for (int r = 0; r < 16; ++r) gacc[ct][T][r] = 0.0f;

    const float* An  = A    + (size_t)n * 6 * VW;
    float*       Aon = Aout + (size_t)n * NC * VW;

    for (int vi = 0; vi < 16; ++vi) {
        const int v = vbase + vi;

        // ================= phase 1: layers 1-2 for position (v, w=t) =======
        const float* ap = An + (size_t)v * NV + t;   // coalesced across t
        const float a0 = ap[0];
        const float a1 = ap[VW];
        const float a2 = ap[2 * VW];
        const float a3 = ap[3 * VW];
        const float a4 = ap[4 * VW];

        float h1v[16];
#pragma unroll
        for (int j = 0; j < 16; ++j) {
            float s = b1[j];
            s = fmaf(w1[j * 5 + 0], a0, s);
            s = fmaf(w1[j * 5 + 1], a1, s);
            s = fmaf(w1[j * 5 + 2], a2, s);
            s = fmaf(w1[j * 5 + 3], a3, s);
            s = fmaf(w1[j * 5 + 4], a4, s);
            h1v[j] = fmaxf(s, 0.0f);
        }
        float h2v[32];
#pragma unroll
        for (int j = 0; j < 32; ++j) {
            float s = b2[j];
#pragma unroll
            for (int i = 0; i < 16; ++i)
                s = fmaf(w2[j * 16 + i], h1v[i], s);
            h2v[j] = fmaxf(s, 0.0f);
        }
        // pack to bf16, write swizzled 16B chunks (chunk c holds k=8c..8c+7)
#pragma unroll
        for (int ch = 0; ch < 4; ++ch) {
            bf16x8 pk;
#pragma unroll
            for (int e = 0; e < 8; ++e) pk[e] = f2bf(h2v[ch * 8 + e]);
            h2s[(t << 2) + (ch ^ ((t >> 1) & 3))] = pk;
        }
        __syncthreads();

        // ================= phase 2: MFMA layer 3 + epilogue ================
        // B frag (K x N = 16 x 32): col=l&31 -> pos, k=(l>>5)*8+e; global
        // k = 16h + 8*hi + e  => chunk = 2h + hi.
        bf16x8 bfr[2][2];
#pragma unroll
        for (int T = 0; T < 2; ++T)
#pragma unroll
            for (int h = 0; h < 2; ++h) {
                const int pos   = (q << 6) + (T << 5) + lo;
                const int chunk = (h << 1) + hi;
                bfr[T][h] = h2s[(pos << 2) + (chunk ^ ((pos >> 1) & 3))];
            }

#pragma unroll
        for (int ct = 0; ct < 2; ++ct)
#pragma unroll
            for (int T = 0; T < 2; ++T) {
                f32x16 d = dinit[ct];
                d = __builtin_amdgcn_mfma_f32_32x32x16_bf16(af[ct][0], bfr[T][0], d, 0, 0, 0);
                d = __builtin_amdgcn_mfma_f32_32x32x16_bf16(af[ct][1], bfr[T][1], d, 0, 0, 0);
                const int w = (q << 6) + (T << 5) + lo;
                float* op = Aon + (size_t)v * NV + w;
#pragma unroll
                for (int r = 0; r < 16; ++r) {
                    // C/D: col=lane&31 (=w), row=(r&3)+8*(r>>2)+4*hi (=c)
                    const int c = (ct << 5) + (r & 3) + ((r >> 2) << 3) + (hi << 2);
                    const float val = 1.0f / (1.0f + __expf(-d[r]));
                    op[(size_t)c * VW] = val;   // half-wave: 128B contiguous
                    gacc[ct][T][r] = fmaf(xocs[c][vi], val, gacc[ct][T][r]);
                }
            }
        __syncthreads();   // protect h2s before next vi's writes
    }

    // ---- gate: one atomic pass per block over its (c,w) tile
    float* pn = post + (size_t)n * (NC * NV);
#pragma unroll
    for (int ct = 0; ct < 2; ++ct)
#pragma unroll
        for (int T = 0; T < 2; ++T) {
            const int w = (q << 6) + (T << 5) + lo;
#pragma unroll
            for (int r = 0; r < 16; ++r) {
                const int c = (ct << 5) + (r & 3) + ((r >> 2) << 3) + (hi << 2);
                atomicAdd(&pn[c * NV + w], gacc[ct][T][r]);
            }
        }
}

// ---------------------------------------------------------------------------
// k3: out1 = x * sigmoid(post)
// ---------------------------------------------------------------------------
__global__ __launch_bounds__(256) void k3_gate(
    const float* __restrict__ x, const float* __restrict__ post,
    float* __restrict__ out1)
{
    const int idx = blockIdx.x * 256 + threadIdx.x;
    const float p = 1.0f / (1.0f + __expf(-post[idx]));
    out1[idx] = x[idx] * p;
}

extern "C" void kernel_launch(void* const* d_in, const int* in_sizes, int n_in,
                              void* d_out, int out_size, void* d_ws, size_t ws_size,
                              hipStream_t stream)
{
    const float* x  = (const float*)d_in[0];
    const float* xo = (const float*)d_in[1];
    const float* A  = (const float*)d_in[2];
    const float* w1 = (const float*)d_in[3];
    const float* b1 = (const float*)d_in[4];
    const float* w2 = (const float*)d_in[5];
    const float* b2 = (const float*)d_in[6];
    const float* w3 = (const float*)d_in[7];
    const float* b3 = (const float*)d_in[8];
    const float* wo = (const float*)d_in[9];
    const float* bo = (const float*)d_in[10];

    float* out1 = (float*)d_out;
    float* Aout = (float*)d_out + NE1;

    float* xoc  = (float*)d_ws;
    float* post = (float*)d_ws + NE1;

    hipMemsetAsync(post, 0, (size_t)NE1 * sizeof(float), stream);
    k1_xoc<<<NE1 / 256, 256, 0, stream>>>(xo, wo, bo, xoc);
    k2_mfma<<<dim3(16, 64), 256, 0, stream>>>(A, w1, b1, w2, b2, w3, b3,
                                              xoc, Aout, post);
    k3_gate<<<NE1 / 256, 256, 0, stream>>>(x, post, out1);
}